// Round 7
// baseline (609.081 us; speedup 1.0000x reference)
//
#include <hip/hip_runtime.h>
#include <stdint.h>

namespace {
constexpr int  kN  = 10000;
constexpr int  kE  = 320000;
constexpr int  kR  = 8;                            // m replicas (atomic sharding)
constexpr long kPOff = 10000;                      // p offset (floats) in d_out
constexpr long kHOff = 10000L + 100000000L;        // h_new offset
constexpr long kTOff = kHOff + 320000L;            // t offset
}

typedef float f32x4 __attribute__((ext_vector_type(4)));

__device__ __forceinline__ float shfl32(float v, int k) { return __shfl(v, k, 32); }

// K1: z = cat[x,h]@W_enc+b_enc ; zwd = z@W_msg[0:32]+b_msg ; zws = z@W_msg[32:64] ;
//     init all kR m-replicas to -inf ; sum_h = 0. One node per half-wave.
__global__ __launch_bounds__(256) void k1_encz(
    const float* __restrict__ x, const float* __restrict__ h,
    const float* __restrict__ W_enc, const float* __restrict__ b_enc,
    const float* __restrict__ W_msg, const float* __restrict__ b_msg,
    float* __restrict__ z, float* __restrict__ zwd, float* __restrict__ zws,
    float* __restrict__ m_rep, float* __restrict__ sum_h)
{
    if (blockIdx.x == 0 && threadIdx.x < 32) sum_h[threadIdx.x] = 0.0f;

    // init replicas: kR*kN*32/4 f32x4 = 640,000 vectors over 1250*256 threads
    {
        const float NEG_INF = -__builtin_inff();
        f32x4 vinf = { NEG_INF, NEG_INF, NEG_INF, NEG_INF };
        f32x4* r4 = reinterpret_cast<f32x4*>(m_rep);
        long total4 = (long)kR * kN * 32 / 4;
        long idx = (long)blockIdx.x * 256 + threadIdx.x;
        long stride = (long)gridDim.x * 256;
        for (long i = idx; i < total4; i += stride) r4[i] = vinf;
    }

    int lane = threadIdx.x & 63;
    int wid  = threadIdx.x >> 6;
    int half = lane >> 5;
    int j    = lane & 31;
    int i = blockIdx.x * 8 + wid * 2 + half;
    if (i >= kN) return;

    float hj = h[(long)i * 32 + j];
    float xi = x[i];
    float zj = fmaf(xi, W_enc[j], b_enc[j]);
#pragma unroll
    for (int k = 0; k < 32; ++k)
        zj = fmaf(shfl32(hj, k), W_enc[(1 + k) * 32 + j], zj);

    z[(long)i * 32 + j] = zj;

    float dv = b_msg[j], sv = 0.0f;
#pragma unroll
    for (int k = 0; k < 32; ++k) {
        float zk = shfl32(zj, k);
        dv = fmaf(zk, W_msg[k * 32 + j], dv);
        sv = fmaf(zk, W_msg[(32 + k) * 32 + j], sv);
    }
    zwd[(long)i * 32 + j] = dv;
    zws[(long)i * 32 + j] = sv;
}

// K2: per-edge msg_j = zwd[d][j]+zws[s][j]+w*Ww_j ; atomic scatter-max into
//     replica (blockIdx & 7) of m. One edge per half-wave, grid-stride.
__global__ __launch_bounds__(256) void k2_msgmax(
    const int* __restrict__ src, const int* __restrict__ dst,
    const float* __restrict__ w, const float* __restrict__ zwd,
    const float* __restrict__ zws, const float* __restrict__ W_msg,
    float* __restrict__ m_rep)
{
    int lane = threadIdx.x & 63;
    int wid  = threadIdx.x >> 6;
    int half = lane >> 5;
    int j    = lane & 31;
    float Ww = W_msg[64 * 32 + j];
    float* mr = m_rep + (long)(blockIdx.x & (kR - 1)) * kN * 32;

    int gw = blockIdx.x * 4 + wid;
    int nw = gridDim.x * 4;
    for (int ep = gw; ep < kE / 2; ep += nw) {
        int e = ep * 2 + half;
        int d = dst[e], s = src[e];
        float val = fmaf(w[e], Ww, zwd[(long)d * 32 + j] + zws[(long)s * 32 + j]);
        float* addr = mr + (long)d * 32 + j;
        if (val >= 0.0f)
            atomicMax(reinterpret_cast<int*>(addr), __float_as_int(val));
        else
            atomicMin(reinterpret_cast<unsigned int*>(addr), __float_as_uint(val));
    }
}

// K3: m = max over replicas (-inf -> 0) ; h_new = cat[z,m]@W_upd+b_upd ;
//     y = cat[z,h_new]@W_dec+b_dec ; a,b = h_new·W_pred halves ; sum_h atomics.
__global__ __launch_bounds__(256) void k3_updn(
    const float* __restrict__ z, const float* __restrict__ m_rep,
    const float* __restrict__ W_upd, const float* __restrict__ b_upd,
    const float* __restrict__ W_dec, const float* __restrict__ b_dec,
    const float* __restrict__ W_pred,
    float* __restrict__ y_out, float* __restrict__ h_out,
    float* __restrict__ a_out, float* __restrict__ b_out,
    float* __restrict__ sum_h)
{
    int i = blockIdx.x * 256 + threadIdx.x;
    bool valid = i < kN;
    int ii = valid ? i : (kN - 1);

    float acc[32];
#pragma unroll
    for (int jj = 0; jj < 32; ++jj) acc[jj] = b_upd[jj];
    float yv = b_dec[0];

    const float4* z4 = reinterpret_cast<const float4*>(z + (long)ii * 32);
#pragma unroll
    for (int q = 0; q < 8; ++q) {
        float4 v = z4[q];
        float in0 = v.x, in1 = v.y, in2 = v.z, in3 = v.w;
        int k = q * 4;
        yv = fmaf(in0, W_dec[k + 0], yv);
        yv = fmaf(in1, W_dec[k + 1], yv);
        yv = fmaf(in2, W_dec[k + 2], yv);
        yv = fmaf(in3, W_dec[k + 3], yv);
        const float* W0 = W_upd + (k + 0) * 32;
        const float* W1 = W_upd + (k + 1) * 32;
        const float* W2 = W_upd + (k + 2) * 32;
        const float* W3 = W_upd + (k + 3) * 32;
#pragma unroll
        for (int jj = 0; jj < 32; ++jj) acc[jj] = fmaf(in0, W0[jj], acc[jj]);
#pragma unroll
        for (int jj = 0; jj < 32; ++jj) acc[jj] = fmaf(in1, W1[jj], acc[jj]);
#pragma unroll
        for (int jj = 0; jj < 32; ++jj) acc[jj] = fmaf(in2, W2[jj], acc[jj]);
#pragma unroll
        for (int jj = 0; jj < 32; ++jj) acc[jj] = fmaf(in3, W3[jj], acc[jj]);
    }

    const float NEG_INF = -__builtin_inff();
#pragma unroll
    for (int q = 0; q < 8; ++q) {
        const float4* m4 = reinterpret_cast<const float4*>(m_rep + (long)ii * 32) + q;
        float4 v = *m4;
#pragma unroll
        for (int r = 1; r < kR; ++r) {
            float4 t = *(m4 + (long)r * kN * 8);
            v.x = fmaxf(v.x, t.x); v.y = fmaxf(v.y, t.y);
            v.z = fmaxf(v.z, t.z); v.w = fmaxf(v.w, t.w);
        }
        float in0 = (v.x == NEG_INF) ? 0.0f : v.x;
        float in1 = (v.y == NEG_INF) ? 0.0f : v.y;
        float in2 = (v.z == NEG_INF) ? 0.0f : v.z;
        float in3 = (v.w == NEG_INF) ? 0.0f : v.w;
        int k = 32 + q * 4;
        const float* W0 = W_upd + (k + 0) * 32;
        const float* W1 = W_upd + (k + 1) * 32;
        const float* W2 = W_upd + (k + 2) * 32;
        const float* W3 = W_upd + (k + 3) * 32;
#pragma unroll
        for (int jj = 0; jj < 32; ++jj) acc[jj] = fmaf(in0, W0[jj], acc[jj]);
#pragma unroll
        for (int jj = 0; jj < 32; ++jj) acc[jj] = fmaf(in1, W1[jj], acc[jj]);
#pragma unroll
        for (int jj = 0; jj < 32; ++jj) acc[jj] = fmaf(in2, W2[jj], acc[jj]);
#pragma unroll
        for (int jj = 0; jj < 32; ++jj) acc[jj] = fmaf(in3, W3[jj], acc[jj]);
    }

    float av = 0.0f, bv = 0.0f;
#pragma unroll
    for (int k = 0; k < 32; ++k) {
        yv = fmaf(acc[k], W_dec[32 + k], yv);
        av = fmaf(acc[k], W_pred[k], av);
        bv = fmaf(acc[k], W_pred[32 + k], bv);
    }

    if (valid) {
        y_out[i] = yv;
        a_out[i] = av;
        b_out[i] = bv;
        float4* hrow = reinterpret_cast<float4*>(h_out + (long)i * 32);
#pragma unroll
        for (int q = 0; q < 8; ++q)
            hrow[q] = make_float4(acc[q * 4 + 0], acc[q * 4 + 1],
                                  acc[q * 4 + 2], acc[q * 4 + 3]);
    }

#pragma unroll
    for (int jj = 0; jj < 32; ++jj) {
        float v = valid ? acc[jj] : 0.0f;
#pragma unroll
        for (int off = 32; off; off >>= 1) v += __shfl_down(v, off, 64);
        if ((threadIdx.x & 63) == 0) atomicAdd(sum_h + jj, v);
    }
}

__global__ __launch_bounds__(256) void k4_fill(float* __restrict__ p)
{
    long idx = (long)blockIdx.x * 256 + threadIdx.x;
    long stride = (long)gridDim.x * 256;
    const long total4 = (long)kN * (long)kN / 4;   // 25,000,000
    f32x4 v = { -1e9f, -1e9f, -1e9f, -1e9f };
    f32x4* p4 = reinterpret_cast<f32x4*>(p);
    for (long i = idx; i < total4; i += stride)
        p4[i] = v;
}

// K5: p[d,s] = a[d]+b[s]+w*W_pred[64]+b_pred ; block 0 wave 0 computes t.
__global__ __launch_bounds__(256) void k5_pred(
    const int* __restrict__ src, const int* __restrict__ dst,
    const float* __restrict__ w, const float* __restrict__ a,
    const float* __restrict__ b, const float* __restrict__ W_pred,
    const float* __restrict__ b_pred, const float* __restrict__ sum_h,
    const float* __restrict__ W_term, const float* __restrict__ b_term,
    float* __restrict__ t_out, float* __restrict__ p)
{
    if (blockIdx.x == 0 && threadIdx.x < 64) {
        int l = threadIdx.x;
        float s = (l < 32) ? (sum_h[l] * (1.0f / (float)kN)) * W_term[l] : 0.0f;
#pragma unroll
        for (int off = 32; off; off >>= 1) s += __shfl_down(s, off, 64);
        if (l == 0) t_out[0] = s + b_term[0];
    }

    int e = blockIdx.x * 256 + threadIdx.x;
    if (e >= kE) return;
    int d = dst[e], s = src[e];
    float score = a[d] + b[s] + fmaf(w[e], W_pred[64], b_pred[0]);
    p[(long)d * kN + s] = score;
}

extern "C" void kernel_launch(void* const* d_in, const int* in_sizes, int n_in,
                              void* d_out, int out_size, void* d_ws, size_t ws_size,
                              hipStream_t stream)
{
    const int*   sources = (const int*)d_in[0];
    const int*   dests   = (const int*)d_in[1];
    const float* weights = (const float*)d_in[2];
    const float* x       = (const float*)d_in[3];
    const float* h       = (const float*)d_in[4];
    const float* W_enc   = (const float*)d_in[5];
    const float* b_enc   = (const float*)d_in[6];
    const float* W_msg   = (const float*)d_in[7];
    const float* b_msg   = (const float*)d_in[8];
    const float* W_upd   = (const float*)d_in[9];
    const float* b_upd   = (const float*)d_in[10];
    const float* W_dec   = (const float*)d_in[11];
    const float* b_dec   = (const float*)d_in[12];
    const float* W_term  = (const float*)d_in[13];
    const float* b_term  = (const float*)d_in[14];
    const float* W_pred  = (const float*)d_in[15];
    const float* b_pred  = (const float*)d_in[16];

    float* out   = (float*)d_out;
    float* y_out = out;
    float* p_out = out + kPOff;
    float* h_out = out + kHOff;
    float* t_out = out + kTOff;

    // workspace layout (all f32); d_ws is ~1.2 GB (poison fill = 1.6 GB total)
    float* z     = (float*)d_ws;                 // N*32
    float* zwd   = z   + (long)kN * 32;          // N*32
    float* zws   = zwd + (long)kN * 32;          // N*32
    float* a_ws  = zws + (long)kN * 32;          // N
    float* b_ws  = a_ws + kN;                    // N
    float* sum_h = b_ws + kN;                    // 32
    float* m_rep = sum_h + 32;                   // kR * N * 32

    k1_encz<<<(kN + 7) / 8, 256, 0, stream>>>(x, h, W_enc, b_enc, W_msg, b_msg,
                                              z, zwd, zws, m_rep, sum_h);
    k2_msgmax<<<2048, 256, 0, stream>>>(sources, dests, weights, zwd, zws, W_msg, m_rep);
    k3_updn<<<(kN + 255) / 256, 256, 0, stream>>>(z, m_rep, W_upd, b_upd, W_dec, b_dec,
                                                  W_pred, y_out, h_out, a_ws, b_ws, sum_h);
    k4_fill<<<8192, 256, 0, stream>>>(p_out);
    k5_pred<<<(kE + 255) / 256, 256, 0, stream>>>(sources, dests, weights, a_ws, b_ws,
                                                  W_pred, b_pred, sum_h, W_term, b_term,
                                                  t_out, p_out);
}

// Round 8
// 590.770 us; speedup vs baseline: 1.0310x; 1.0310x over previous
//
#include <hip/hip_runtime.h>
#include <stdint.h>

namespace {
constexpr int  kN  = 10000;
constexpr int  kE  = 320000;
constexpr long kPOff = 10000;                      // p offset (floats) in d_out
constexpr long kHOff = 10000L + 100000000L;        // h_new offset
constexpr long kTOff = kHOff + 320000L;            // t offset
constexpr long kP4   = (long)kN * kN / 4;          // 25,000,000 f32x4
}

typedef float f32x4 __attribute__((ext_vector_type(4)));

__device__ __forceinline__ float shfl32(float v, int k) { return __shfl(v, k, 32); }

// K1: z = cat[x,h]@W_enc+b_enc ; zwd = z@W_msg[0:32]+b_msg ; zws = z@W_msg[32:64] ;
//     m = -inf ; sum_h = 0. One node per half-wave, lane j = channel j.
__global__ __launch_bounds__(256) void k1_encz(
    const float* __restrict__ x, const float* __restrict__ h,
    const float* __restrict__ W_enc, const float* __restrict__ b_enc,
    const float* __restrict__ W_msg, const float* __restrict__ b_msg,
    float* __restrict__ z, float* __restrict__ zwd, float* __restrict__ zws,
    float* __restrict__ m, float* __restrict__ sum_h)
{
    if (blockIdx.x == 0 && threadIdx.x < 32) sum_h[threadIdx.x] = 0.0f;

    int lane = threadIdx.x & 63;
    int wid  = threadIdx.x >> 6;
    int half = lane >> 5;
    int j    = lane & 31;
    int i = blockIdx.x * 8 + wid * 2 + half;
    if (i >= kN) return;

    float hj = h[(long)i * 32 + j];
    float xi = x[i];
    float zj = fmaf(xi, W_enc[j], b_enc[j]);
#pragma unroll
    for (int k = 0; k < 32; ++k)
        zj = fmaf(shfl32(hj, k), W_enc[(1 + k) * 32 + j], zj);

    z[(long)i * 32 + j] = zj;
    m[(long)i * 32 + j] = -__builtin_inff();

    float dv = b_msg[j], sv = 0.0f;
#pragma unroll
    for (int k = 0; k < 32; ++k) {
        float zk = shfl32(zj, k);
        dv = fmaf(zk, W_msg[k * 32 + j], dv);
        sv = fmaf(zk, W_msg[(32 + k) * 32 + j], sv);
    }
    zwd[(long)i * 32 + j] = dv;
    zws[(long)i * 32 + j] = sv;
}

// K2: block-role split.
//   odd blocks  (1024): fill p with -1e9 (pure write-BW role)
//   even blocks (1024): per-edge msg_j = zwd[d][j]+zws[s][j]+w*Ww_j,
//                       atomic scatter-max into m[d] (latency/atomic role)
// Independent work -> waves co-schedule, time ~= max(fill, msgmax).
__global__ __launch_bounds__(256) void k2_work(
    const int* __restrict__ src, const int* __restrict__ dst,
    const float* __restrict__ w, const float* __restrict__ zwd,
    const float* __restrict__ zws, const float* __restrict__ W_msg,
    float* __restrict__ m, float* __restrict__ p)
{
    if (blockIdx.x & 1) {
        // -------- fill role --------
        long fb = blockIdx.x >> 1;                   // 0..1023
        long idx = fb * 256 + threadIdx.x;
        long stride = 1024L * 256;
        f32x4 v = { -1e9f, -1e9f, -1e9f, -1e9f };
        f32x4* p4 = reinterpret_cast<f32x4*>(p);
        for (long i = idx; i < kP4; i += stride)
            p4[i] = v;
    } else {
        // -------- msgmax role --------
        int lane = threadIdx.x & 63;
        int wid  = threadIdx.x >> 6;
        int half = lane >> 5;
        int j    = lane & 31;
        float Ww = W_msg[64 * 32 + j];
        int mb = blockIdx.x >> 1;                    // 0..1023
        int gw = mb * 4 + wid;
        int nw = 1024 * 4;
        for (int ep = gw; ep < kE / 2; ep += nw) {
            int e = ep * 2 + half;
            int d = dst[e], s = src[e];
            float val = fmaf(w[e], Ww, zwd[(long)d * 32 + j] + zws[(long)s * 32 + j]);
            float* addr = m + (long)d * 32 + j;
            if (val >= 0.0f)
                atomicMax(reinterpret_cast<int*>(addr), __float_as_int(val));
            else
                atomicMin(reinterpret_cast<unsigned int*>(addr), __float_as_uint(val));
        }
    }
}

// K3: h_new = cat[z,m0]@W_upd+b_upd ; y = cat[z,h_new]@W_dec+b_dec ;
//     a = h_new·W_pred[0:32] ; b = h_new·W_pred[32:64] ; sum_h wave-partial atomics.
__global__ __launch_bounds__(256) void k3_updn(
    const float* __restrict__ z, const float* __restrict__ m,
    const float* __restrict__ W_upd, const float* __restrict__ b_upd,
    const float* __restrict__ W_dec, const float* __restrict__ b_dec,
    const float* __restrict__ W_pred,
    float* __restrict__ y_out, float* __restrict__ h_out,
    float* __restrict__ a_out, float* __restrict__ b_out,
    float* __restrict__ sum_h)
{
    int i = blockIdx.x * 256 + threadIdx.x;
    bool valid = i < kN;
    int ii = valid ? i : (kN - 1);

    float acc[32];
#pragma unroll
    for (int jj = 0; jj < 32; ++jj) acc[jj] = b_upd[jj];
    float yv = b_dec[0];

    const float4* z4 = reinterpret_cast<const float4*>(z + (long)ii * 32);
#pragma unroll
    for (int q = 0; q < 8; ++q) {
        float4 v = z4[q];
        float in0 = v.x, in1 = v.y, in2 = v.z, in3 = v.w;
        int k = q * 4;
        yv = fmaf(in0, W_dec[k + 0], yv);
        yv = fmaf(in1, W_dec[k + 1], yv);
        yv = fmaf(in2, W_dec[k + 2], yv);
        yv = fmaf(in3, W_dec[k + 3], yv);
        const float* W0 = W_upd + (k + 0) * 32;
        const float* W1 = W_upd + (k + 1) * 32;
        const float* W2 = W_upd + (k + 2) * 32;
        const float* W3 = W_upd + (k + 3) * 32;
#pragma unroll
        for (int jj = 0; jj < 32; ++jj) acc[jj] = fmaf(in0, W0[jj], acc[jj]);
#pragma unroll
        for (int jj = 0; jj < 32; ++jj) acc[jj] = fmaf(in1, W1[jj], acc[jj]);
#pragma unroll
        for (int jj = 0; jj < 32; ++jj) acc[jj] = fmaf(in2, W2[jj], acc[jj]);
#pragma unroll
        for (int jj = 0; jj < 32; ++jj) acc[jj] = fmaf(in3, W3[jj], acc[jj]);
    }

    const float NEG_INF = -__builtin_inff();
    const float4* m4 = reinterpret_cast<const float4*>(m + (long)ii * 32);
#pragma unroll
    for (int q = 0; q < 8; ++q) {
        float4 v = m4[q];
        float in0 = (v.x == NEG_INF) ? 0.0f : v.x;
        float in1 = (v.y == NEG_INF) ? 0.0f : v.y;
        float in2 = (v.z == NEG_INF) ? 0.0f : v.z;
        float in3 = (v.w == NEG_INF) ? 0.0f : v.w;
        int k = 32 + q * 4;
        const float* W0 = W_upd + (k + 0) * 32;
        const float* W1 = W_upd + (k + 1) * 32;
        const float* W2 = W_upd + (k + 2) * 32;
        const float* W3 = W_upd + (k + 3) * 32;
#pragma unroll
        for (int jj = 0; jj < 32; ++jj) acc[jj] = fmaf(in0, W0[jj], acc[jj]);
#pragma unroll
        for (int jj = 0; jj < 32; ++jj) acc[jj] = fmaf(in1, W1[jj], acc[jj]);
#pragma unroll
        for (int jj = 0; jj < 32; ++jj) acc[jj] = fmaf(in2, W2[jj], acc[jj]);
#pragma unroll
        for (int jj = 0; jj < 32; ++jj) acc[jj] = fmaf(in3, W3[jj], acc[jj]);
    }

    float av = 0.0f, bv = 0.0f;
#pragma unroll
    for (int k = 0; k < 32; ++k) {
        yv = fmaf(acc[k], W_dec[32 + k], yv);
        av = fmaf(acc[k], W_pred[k], av);
        bv = fmaf(acc[k], W_pred[32 + k], bv);
    }

    if (valid) {
        y_out[i] = yv;
        a_out[i] = av;
        b_out[i] = bv;
        float4* hrow = reinterpret_cast<float4*>(h_out + (long)i * 32);
#pragma unroll
        for (int q = 0; q < 8; ++q)
            hrow[q] = make_float4(acc[q * 4 + 0], acc[q * 4 + 1],
                                  acc[q * 4 + 2], acc[q * 4 + 3]);
    }

#pragma unroll
    for (int jj = 0; jj < 32; ++jj) {
        float v = valid ? acc[jj] : 0.0f;
#pragma unroll
        for (int off = 32; off; off >>= 1) v += __shfl_down(v, off, 64);
        if ((threadIdx.x & 63) == 0) atomicAdd(sum_h + jj, v);
    }
}

// K4: p[d,s] = a[d]+b[s]+w*W_pred[64]+b_pred ; block 0 wave 0 computes t.
__global__ __launch_bounds__(256) void k4_pred(
    const int* __restrict__ src, const int* __restrict__ dst,
    const float* __restrict__ w, const float* __restrict__ a,
    const float* __restrict__ b, const float* __restrict__ W_pred,
    const float* __restrict__ b_pred, const float* __restrict__ sum_h,
    const float* __restrict__ W_term, const float* __restrict__ b_term,
    float* __restrict__ t_out, float* __restrict__ p)
{
    if (blockIdx.x == 0 && threadIdx.x < 64) {
        int l = threadIdx.x;
        float s = (l < 32) ? (sum_h[l] * (1.0f / (float)kN)) * W_term[l] : 0.0f;
#pragma unroll
        for (int off = 32; off; off >>= 1) s += __shfl_down(s, off, 64);
        if (l == 0) t_out[0] = s + b_term[0];
    }

    int e = blockIdx.x * 256 + threadIdx.x;
    if (e >= kE) return;
    int d = dst[e], s = src[e];
    float score = a[d] + b[s] + fmaf(w[e], W_pred[64], b_pred[0]);
    p[(long)d * kN + s] = score;
}

extern "C" void kernel_launch(void* const* d_in, const int* in_sizes, int n_in,
                              void* d_out, int out_size, void* d_ws, size_t ws_size,
                              hipStream_t stream)
{
    const int*   sources = (const int*)d_in[0];
    const int*   dests   = (const int*)d_in[1];
    const float* weights = (const float*)d_in[2];
    const float* x       = (const float*)d_in[3];
    const float* h       = (const float*)d_in[4];
    const float* W_enc   = (const float*)d_in[5];
    const float* b_enc   = (const float*)d_in[6];
    const float* W_msg   = (const float*)d_in[7];
    const float* b_msg   = (const float*)d_in[8];
    const float* W_upd   = (const float*)d_in[9];
    const float* b_upd   = (const float*)d_in[10];
    const float* W_dec   = (const float*)d_in[11];
    const float* b_dec   = (const float*)d_in[12];
    const float* W_term  = (const float*)d_in[13];
    const float* b_term  = (const float*)d_in[14];
    const float* W_pred  = (const float*)d_in[15];
    const float* b_pred  = (const float*)d_in[16];

    float* out   = (float*)d_out;
    float* y_out = out;
    float* p_out = out + kPOff;
    float* h_out = out + kHOff;
    float* t_out = out + kTOff;

    // workspace layout (all f32)
    float* z     = (float*)d_ws;                 // N*32
    float* m     = z   + (long)kN * 32;          // N*32
    float* zwd   = m   + (long)kN * 32;          // N*32
    float* zws   = zwd + (long)kN * 32;          // N*32
    float* a_ws  = zws + (long)kN * 32;          // N
    float* b_ws  = a_ws + kN;                    // N
    float* sum_h = b_ws + kN;                    // 32

    k1_encz<<<(kN + 7) / 8, 256, 0, stream>>>(x, h, W_enc, b_enc, W_msg, b_msg,
                                              z, zwd, zws, m, sum_h);
    k2_work<<<2048, 256, 0, stream>>>(sources, dests, weights, zwd, zws, W_msg,
                                      m, p_out);
    k3_updn<<<(kN + 255) / 256, 256, 0, stream>>>(z, m, W_upd, b_upd, W_dec, b_dec,
                                                  W_pred, y_out, h_out, a_ws, b_ws, sum_h);
    k4_pred<<<(kE + 255) / 256, 256, 0, stream>>>(sources, dests, weights, a_ws, b_ws,
                                                  W_pred, b_pred, sum_h, W_term, b_term,
                                                  t_out, p_out);
}

// Round 9
// 560.616 us; speedup vs baseline: 1.0864x; 1.0538x over previous
//
#include <hip/hip_runtime.h>
#include <stdint.h>

namespace {
constexpr int  kN  = 10000;
constexpr int  kE  = 320000;
constexpr long kPOff = 10000;                      // p offset (floats) in d_out
constexpr long kHOff = 10000L + 100000000L;        // h_new offset
constexpr long kTOff = kHOff + 320000L;            // t offset
constexpr long kP4   = (long)kN * kN / 4;          // 25,000,000 f32x4
constexpr int  kEncBlocks  = (kN + 7) / 8;         // 1250
constexpr int  kFillBlocks = 4096;
}

typedef float f32x4 __attribute__((ext_vector_type(4)));

__device__ __forceinline__ float shfl32(float v, int k) { return __shfl(v, k, 32); }

// K1: block-role split.
//   blocks [0,1250):        encz — z = cat[x,h]@W_enc+b_enc ; zwd = z@Wm[0:32]+b ;
//                           zws = z@Wm[32:64] ; m = -inf. One node per half-wave.
//   blocks [1250,1250+4096): fill p with -1e9 (pure write-BW role, overlaps encz)
__global__ __launch_bounds__(256) void k1_encz_fill(
    const float* __restrict__ x, const float* __restrict__ h,
    const float* __restrict__ W_enc, const float* __restrict__ b_enc,
    const float* __restrict__ W_msg, const float* __restrict__ b_msg,
    float* __restrict__ z, float* __restrict__ zwd, float* __restrict__ zws,
    float* __restrict__ m, float* __restrict__ p)
{
    if (blockIdx.x >= kEncBlocks) {
        // -------- fill role --------
        long fb = blockIdx.x - kEncBlocks;           // 0..4095
        long idx = fb * 256 + threadIdx.x;
        long stride = (long)kFillBlocks * 256;
        f32x4 v = { -1e9f, -1e9f, -1e9f, -1e9f };
        f32x4* p4 = reinterpret_cast<f32x4*>(p);
        for (long i = idx; i < kP4; i += stride)
            p4[i] = v;
        return;
    }

    // -------- encz role --------
    int lane = threadIdx.x & 63;
    int wid  = threadIdx.x >> 6;
    int half = lane >> 5;
    int j    = lane & 31;
    int i = blockIdx.x * 8 + wid * 2 + half;
    if (i >= kN) return;

    float hj = h[(long)i * 32 + j];
    float xi = x[i];
    float zj = fmaf(xi, W_enc[j], b_enc[j]);
#pragma unroll
    for (int k = 0; k < 32; ++k)
        zj = fmaf(shfl32(hj, k), W_enc[(1 + k) * 32 + j], zj);

    z[(long)i * 32 + j] = zj;
    m[(long)i * 32 + j] = -__builtin_inff();

    float dv = b_msg[j], sv = 0.0f;
#pragma unroll
    for (int k = 0; k < 32; ++k) {
        float zk = shfl32(zj, k);
        dv = fmaf(zk, W_msg[k * 32 + j], dv);
        sv = fmaf(zk, W_msg[(32 + k) * 32 + j], sv);
    }
    zwd[(long)i * 32 + j] = dv;
    zws[(long)i * 32 + j] = sv;
}

// K2: per-edge msg_j = zwd[d][j]+zws[s][j]+w*Ww_j ; atomic scatter-max into m[d].
// One edge per half-wave, grid-stride. (r4-identical)
__global__ __launch_bounds__(256) void k2_msgmax(
    const int* __restrict__ src, const int* __restrict__ dst,
    const float* __restrict__ w, const float* __restrict__ zwd,
    const float* __restrict__ zws, const float* __restrict__ W_msg,
    float* __restrict__ m)
{
    int lane = threadIdx.x & 63;
    int wid  = threadIdx.x >> 6;
    int half = lane >> 5;
    int j    = lane & 31;
    float Ww = W_msg[64 * 32 + j];
    int gw = blockIdx.x * 4 + wid;
    int nw = gridDim.x * 4;
    for (int ep = gw; ep < kE / 2; ep += nw) {
        int e = ep * 2 + half;
        int d = dst[e], s = src[e];
        float val = fmaf(w[e], Ww, zwd[(long)d * 32 + j] + zws[(long)s * 32 + j]);
        float* addr = m + (long)d * 32 + j;
        if (val >= 0.0f)
            atomicMax(reinterpret_cast<int*>(addr), __float_as_int(val));
        else
            atomicMin(reinterpret_cast<unsigned int*>(addr), __float_as_uint(val));
    }
}

// K3: h_new = cat[z,m0]@W_upd+b_upd ; y = cat[z,h_new]@W_dec+b_dec ;
//     a = h_new·W_pred[0:32] ; b = h_new·W_pred[32:64] ; per-wave h_new partials.
__global__ __launch_bounds__(256) void k3_updn(
    const float* __restrict__ z, const float* __restrict__ m,
    const float* __restrict__ W_upd, const float* __restrict__ b_upd,
    const float* __restrict__ W_dec, const float* __restrict__ b_dec,
    const float* __restrict__ W_pred,
    float* __restrict__ y_out, float* __restrict__ h_out,
    float* __restrict__ a_out, float* __restrict__ b_out,
    float* __restrict__ partials)
{
    int i = blockIdx.x * 256 + threadIdx.x;
    bool valid = i < kN;
    int ii = valid ? i : (kN - 1);

    float acc[32];
#pragma unroll
    for (int jj = 0; jj < 32; ++jj) acc[jj] = b_upd[jj];
    float yv = b_dec[0];

    const float4* z4 = reinterpret_cast<const float4*>(z + (long)ii * 32);
#pragma unroll
    for (int q = 0; q < 8; ++q) {
        float4 v = z4[q];
        float in0 = v.x, in1 = v.y, in2 = v.z, in3 = v.w;
        int k = q * 4;
        yv = fmaf(in0, W_dec[k + 0], yv);
        yv = fmaf(in1, W_dec[k + 1], yv);
        yv = fmaf(in2, W_dec[k + 2], yv);
        yv = fmaf(in3, W_dec[k + 3], yv);
        const float* W0 = W_upd + (k + 0) * 32;
        const float* W1 = W_upd + (k + 1) * 32;
        const float* W2 = W_upd + (k + 2) * 32;
        const float* W3 = W_upd + (k + 3) * 32;
#pragma unroll
        for (int jj = 0; jj < 32; ++jj) acc[jj] = fmaf(in0, W0[jj], acc[jj]);
#pragma unroll
        for (int jj = 0; jj < 32; ++jj) acc[jj] = fmaf(in1, W1[jj], acc[jj]);
#pragma unroll
        for (int jj = 0; jj < 32; ++jj) acc[jj] = fmaf(in2, W2[jj], acc[jj]);
#pragma unroll
        for (int jj = 0; jj < 32; ++jj) acc[jj] = fmaf(in3, W3[jj], acc[jj]);
    }

    const float NEG_INF = -__builtin_inff();
    const float4* m4 = reinterpret_cast<const float4*>(m + (long)ii * 32);
#pragma unroll
    for (int q = 0; q < 8; ++q) {
        float4 v = m4[q];
        float in0 = (v.x == NEG_INF) ? 0.0f : v.x;
        float in1 = (v.y == NEG_INF) ? 0.0f : v.y;
        float in2 = (v.z == NEG_INF) ? 0.0f : v.z;
        float in3 = (v.w == NEG_INF) ? 0.0f : v.w;
        int k = 32 + q * 4;
        const float* W0 = W_upd + (k + 0) * 32;
        const float* W1 = W_upd + (k + 1) * 32;
        const float* W2 = W_upd + (k + 2) * 32;
        const float* W3 = W_upd + (k + 3) * 32;
#pragma unroll
        for (int jj = 0; jj < 32; ++jj) acc[jj] = fmaf(in0, W0[jj], acc[jj]);
#pragma unroll
        for (int jj = 0; jj < 32; ++jj) acc[jj] = fmaf(in1, W1[jj], acc[jj]);
#pragma unroll
        for (int jj = 0; jj < 32; ++jj) acc[jj] = fmaf(in2, W2[jj], acc[jj]);
#pragma unroll
        for (int jj = 0; jj < 32; ++jj) acc[jj] = fmaf(in3, W3[jj], acc[jj]);
    }

    float av = 0.0f, bv = 0.0f;
#pragma unroll
    for (int k = 0; k < 32; ++k) {
        yv = fmaf(acc[k], W_dec[32 + k], yv);
        av = fmaf(acc[k], W_pred[k], av);
        bv = fmaf(acc[k], W_pred[32 + k], bv);
    }

    if (valid) {
        y_out[i] = yv;
        a_out[i] = av;
        b_out[i] = bv;
        float4* hrow = reinterpret_cast<float4*>(h_out + (long)i * 32);
#pragma unroll
        for (int q = 0; q < 8; ++q)
            hrow[q] = make_float4(acc[q * 4 + 0], acc[q * 4 + 1],
                                  acc[q * 4 + 2], acc[q * 4 + 3]);
    }

    // per-wave partial sums of h_new -> global (no atomics); 40 blocks * 4 waves = 160
    int wslot = blockIdx.x * 4 + ((threadIdx.x >> 6) & 3);
#pragma unroll
    for (int jj = 0; jj < 32; ++jj) {
        float v = valid ? acc[jj] : 0.0f;
#pragma unroll
        for (int off = 32; off; off >>= 1) v += __shfl_down(v, off, 64);
        if ((threadIdx.x & 63) == 0) partials[(long)wslot * 32 + jj] = v;
    }
}

// K4: p[d,s] = a[d]+b[s]+w*W_pred[64]+b_pred ; block 0 wave 0 reduces partials -> t.
__global__ __launch_bounds__(256) void k4_pred(
    const int* __restrict__ src, const int* __restrict__ dst,
    const float* __restrict__ w, const float* __restrict__ a,
    const float* __restrict__ b, const float* __restrict__ W_pred,
    const float* __restrict__ b_pred, const float* __restrict__ partials,
    const float* __restrict__ W_term, const float* __restrict__ b_term,
    float* __restrict__ t_out, float* __restrict__ p)
{
    if (blockIdx.x == 0 && threadIdx.x < 64) {
        int l = threadIdx.x;
        float s = 0.0f;
        if (l < 32) {
            for (int r = 0; r < 160; ++r) s += partials[(long)r * 32 + l];
            s = (s * (1.0f / (float)kN)) * W_term[l];
        }
#pragma unroll
        for (int off = 32; off; off >>= 1) s += __shfl_down(s, off, 64);
        if (l == 0) t_out[0] = s + b_term[0];
    }

    int e = blockIdx.x * 256 + threadIdx.x;
    if (e >= kE) return;
    int d = dst[e], s = src[e];
    float score = a[d] + b[s] + fmaf(w[e], W_pred[64], b_pred[0]);
    p[(long)d * kN + s] = score;
}

extern "C" void kernel_launch(void* const* d_in, const int* in_sizes, int n_in,
                              void* d_out, int out_size, void* d_ws, size_t ws_size,
                              hipStream_t stream)
{
    const int*   sources = (const int*)d_in[0];
    const int*   dests   = (const int*)d_in[1];
    const float* weights = (const float*)d_in[2];
    const float* x       = (const float*)d_in[3];
    const float* h       = (const float*)d_in[4];
    const float* W_enc   = (const float*)d_in[5];
    const float* b_enc   = (const float*)d_in[6];
    const float* W_msg   = (const float*)d_in[7];
    const float* b_msg   = (const float*)d_in[8];
    const float* W_upd   = (const float*)d_in[9];
    const float* b_upd   = (const float*)d_in[10];
    const float* W_dec   = (const float*)d_in[11];
    const float* b_dec   = (const float*)d_in[12];
    const float* W_term  = (const float*)d_in[13];
    const float* b_term  = (const float*)d_in[14];
    const float* W_pred  = (const float*)d_in[15];
    const float* b_pred  = (const float*)d_in[16];

    float* out   = (float*)d_out;
    float* y_out = out;
    float* p_out = out + kPOff;
    float* h_out = out + kHOff;
    float* t_out = out + kTOff;

    // workspace layout (all f32)
    float* z        = (float*)d_ws;                  // N*32
    float* m        = z   + (long)kN * 32;           // N*32
    float* zwd      = m   + (long)kN * 32;           // N*32
    float* zws      = zwd + (long)kN * 32;           // N*32
    float* a_ws     = zws + (long)kN * 32;           // N
    float* b_ws     = a_ws + kN;                     // N
    float* partials = b_ws + kN;                     // 160*32

    k1_encz_fill<<<kEncBlocks + kFillBlocks, 256, 0, stream>>>(
        x, h, W_enc, b_enc, W_msg, b_msg, z, zwd, zws, m, p_out);
    k2_msgmax<<<10000, 256, 0, stream>>>(sources, dests, weights, zwd, zws, W_msg, m);
    k3_updn<<<(kN + 255) / 256, 256, 0, stream>>>(z, m, W_upd, b_upd, W_dec, b_dec,
                                                  W_pred, y_out, h_out, a_ws, b_ws,
                                                  partials);
    k4_pred<<<(kE + 255) / 256, 256, 0, stream>>>(sources, dests, weights, a_ws, b_ws,
                                                  W_pred, b_pred, partials, W_term, b_term,
                                                  t_out, p_out);
}